// Round 8
// baseline (263.362 us; speedup 1.0000x reference)
//
#include <hip/hip_runtime.h>
#include <hip/hip_bf16.h>

typedef __bf16 bf16_t;
typedef __bf16 bf16x8 __attribute__((ext_vector_type(8)));
typedef float f32x4 __attribute__((ext_vector_type(4)));
typedef float f32x16 __attribute__((ext_vector_type(16)));

#define MTOT 8192
#define CDIM 1024
#define HEADS 8
#define DV 128
#define QKD 128
#define SEQ 2048
#define QSCALE 0.3606737602222409f   // 0.25 * log2(e): softmax scale folded into Q

struct alignas(8) B4 { bf16_t a, b, c, d; };

__device__ inline bf16x8 cvt8(float4 a, float4 b) {
    bf16x8 v = { (bf16_t)a.x, (bf16_t)a.y, (bf16_t)a.z, (bf16_t)a.w,
                 (bf16_t)b.x, (bf16_t)b.y, (bf16_t)b.z, (bf16_t)b.w };
    return v;
}

// packed f32->bf16 pair: dst = {lo16=cvt(a), hi16=cvt(b)}  (T12; no builtin)
__device__ inline unsigned cvtpk(float a, float b) {
    unsigned r;
    asm("v_cvt_pk_bf16_f32 %0, %1, %2" : "=v"(r) : "v"(a), "v"(b));
    return r;
}

// v_permlane32_swap_b32: a.hi32lanes <-> b.lo32lanes (in place)
__device__ inline void plswap(unsigned& a, unsigned& b) {
    asm("v_permlane32_swap_b32 %0, %1" : "+v"(a), "+v"(b));
}

// ---------------------------------------------------------------------------
// QKV GEMM, fp32 inputs, in-register bf16 cvt, 128x128 tile (R7-proven).
// grid (10, 64). bx0 -> Q (xQSCALE), bx1 -> K, bx2..9 -> V head (bx-2) transp.
// Single launch replaces cvt_all + qkv_gemm3 (launch-overhead decomposition).
// ---------------------------------------------------------------------------
__global__ __launch_bounds__(256, 2) void qkv_gemm2(
    const float* __restrict__ X,
    const float* __restrict__ Wq, const float* __restrict__ bq,
    const float* __restrict__ Wk, const float* __restrict__ bk,
    const float* __restrict__ Wv, const float* __restrict__ bv,
    bf16_t* __restrict__ Qw, bf16_t* __restrict__ Kw, bf16_t* __restrict__ Vt)
{
    __shared__ alignas(16) bf16_t As[128][72];
    __shared__ alignas(16) bf16_t Bs[128][72];

    const int tid  = threadIdx.x;
    const int lane = tid & 63, wave = tid >> 6;
    const int c = lane & 15, q = lane >> 4;
    const int rw = wave & 1, cw = wave >> 1;
    const int m0 = blockIdx.y * 128;
    const int nt_idx = blockIdx.x;

    const float* W; const float* bias;
    if (nt_idx == 0)      { W = Wq; bias = bq; }
    else if (nt_idx == 1) { W = Wk; bias = bk; }
    else { W = Wv + (size_t)(nt_idx - 2) * DV * CDIM; bias = bv + (nt_idx - 2) * DV; }

    const int srow = tid >> 1, sseg = tid & 1;
    const int swr = (srow >> 3) & 3;
    const float* ax = X + (size_t)(m0 + srow) * CDIM + sseg * 32;
    const float* bxp = W + (size_t)srow * CDIM + sseg * 32;

    f32x4 acc[16] = {};

    for (int k0 = 0; k0 < CDIM; k0 += 64) {
        __syncthreads();
        #pragma unroll
        for (int i = 0; i < 4; ++i) {
            const int ph = (sseg * 4 + i) ^ swr;
            *(bf16x8*)&As[srow][ph * 8] = cvt8(*(const float4*)(ax + k0 + i * 8),
                                               *(const float4*)(ax + k0 + i * 8 + 4));
            *(bf16x8*)&Bs[srow][ph * 8] = cvt8(*(const float4*)(bxp + k0 + i * 8),
                                               *(const float4*)(bxp + k0 + i * 8 + 4));
        }
        __syncthreads();
        #pragma unroll
        for (int kk = 0; kk < 2; ++kk) {
            bf16x8 af[4], bfr[4];
            #pragma unroll
            for (int mt = 0; mt < 4; ++mt) {
                const int row = rw * 64 + mt * 16 + c;
                af[mt] = *(const bf16x8*)&As[row][((kk * 4 + q) ^ ((row >> 3) & 3)) * 8];
            }
            #pragma unroll
            for (int nt = 0; nt < 4; ++nt) {
                const int row = cw * 64 + nt * 16 + c;
                bfr[nt] = *(const bf16x8*)&Bs[row][((kk * 4 + q) ^ ((row >> 3) & 3)) * 8];
            }
            #pragma unroll
            for (int mt = 0; mt < 4; ++mt)
                #pragma unroll
                for (int nt = 0; nt < 4; ++nt)
                    acc[mt * 4 + nt] = __builtin_amdgcn_mfma_f32_16x16x32_bf16(
                        af[mt], bfr[nt], acc[mt * 4 + nt], 0, 0, 0);
        }
    }

    #pragma unroll
    for (int mt = 0; mt < 4; ++mt)
        #pragma unroll
        for (int nt = 0; nt < 4; ++nt) {
            const int col = cw * 64 + nt * 16 + c;
            const float bb = bias[col];
            f32x4 a = acc[mt * 4 + nt];
            const int mg = m0 + rw * 64 + mt * 16 + q * 4;
            if (nt_idx == 0) {
                #pragma unroll
                for (int r = 0; r < 4; ++r)
                    Qw[(size_t)(mg + r) * QKD + col] = (bf16_t)((a[r] + bb) * QSCALE);
            } else if (nt_idx == 1) {
                #pragma unroll
                for (int r = 0; r < 4; ++r)
                    Kw[(size_t)(mg + r) * QKD + col] = (bf16_t)(a[r] + bb);
            } else {
                const int h = nt_idx - 2;
                const int bidx = mg >> 11, ml = mg & 2047;
                B4 v{ (bf16_t)(a[0] + bb), (bf16_t)(a[1] + bb),
                      (bf16_t)(a[2] + bb), (bf16_t)(a[3] + bb) };
                *(B4*)(Vt + ((size_t)(bidx * HEADS + h) * DV + col) * SEQ + ml) = v;
            }
        }
}

// ---------------------------------------------------------------------------
// Flash attention, 32x32x16 MFMA. One WG = one (b,h) x 128 q-rows.
// R3-exact (best measured: 64.5 us): KVBLK=64, single __syncthreads/iter,
// T12 in-register P (cvt_pk + permlane32_swap), Vs LDS double-buffer,
// 2-deep V/K register prefetch, setprio around PV, XCD-clustered mapping.
// ---------------------------------------------------------------------------
__global__ __launch_bounds__(256, 2) void attn3(
    const bf16_t* __restrict__ Q, const bf16_t* __restrict__ K,
    const bf16_t* __restrict__ Vt, const float* __restrict__ X,
    const float* __restrict__ gptr, float* __restrict__ out)
{
    __shared__ alignas(16) bf16_t Vs[2][128][72];   // 36.9 KB double buffer

    const int tid  = threadIdx.x;
    const int lane = tid & 63;
    const int c5 = lane & 31, q1 = lane >> 5;

    // XCD-cluster swizzle: each XCD gets 4 (b,h) heads x all 16 q-tiles.
    const int lin = blockIdx.x + (SEQ / 128) * blockIdx.y;  // 0..511
    const int xcd = lin & 7, jj = lin >> 3;                 // jj 0..63
    const int bh = xcd * 4 + (jj >> 4);
    const int qt = jj & 15;
    const int b = bh >> 3, h = bh & 7;
    const int wave = tid >> 6;
    const int mbase = qt * 128 + wave * 32;

    const bf16x8 qf = *(const bf16x8*)(
        Q + (size_t)(b * SEQ + mbase + c5) * QKD + h * 16 + q1 * 8);

    float li = 0.f;
    f32x16 o[4] = {};

    const bf16_t* Vhead = Vt + (size_t)(b * HEADS + h) * DV * SEQ;
    const bf16_t* Kbase = K + (size_t)(b * SEQ) * QKD + h * 16;

    const int sdv = tid >> 1, sseg = tid & 1;
    const int swv = (sdv >> 3) & 7;

    // vA: even tiles, vB: odd tiles (tile = 64 kv rows). kA even, kB odd.
    bf16x8 vA[4], vB[4], kA[2], kB[2];

    // ---- prologue: issue tiles 0 and 1 ----
    {
        const bf16_t* s0 = Vhead + (size_t)sdv * SEQ + sseg * 32;
        #pragma unroll
        for (int i = 0; i < 4; ++i) vA[i] = *(const bf16x8*)(s0 + i * 8);
        const bf16_t* s1 = s0 + 64;
        #pragma unroll
        for (int i = 0; i < 4; ++i) vB[i] = *(const bf16x8*)(s1 + i * 8);
        #pragma unroll
        for (int blk = 0; blk < 2; ++blk) {
            kA[blk] = *(const bf16x8*)(Kbase + (size_t)(blk * 32 + c5) * QKD + q1 * 8);
            kB[blk] = *(const bf16x8*)(Kbase + (size_t)(64 + blk * 32 + c5) * QKD + q1 * 8);
        }
        // write tile 0 into Vs[0]; reissue vA <- tile 2
        #pragma unroll
        for (int i = 0; i < 4; ++i) {
            const int ph = (sseg * 4 + i) ^ swv;
            *(bf16x8*)&Vs[0][sdv][ph * 8] = vA[i];
        }
        const bf16_t* s2 = s0 + 128;
        #pragma unroll
        for (int i = 0; i < 4; ++i) vA[i] = *(const bf16x8*)(s2 + i * 8);
    }

    union U8 { bf16x8 v; unsigned u[4]; };

    #pragma unroll 1
    for (int t = 0; t < 32; t += 2) {
        #pragma unroll
        for (int half = 0; half < 2; ++half) {
            // half 0: tile t   (read Vs[0], stage vB->Vs[1], reissue vB,kA)
            // half 1: tile t+1 (read Vs[1], stage vA->Vs[0], reissue vA,kB)
            __syncthreads();     // prev PV readers done; staged buffer visible
            #pragma unroll
            for (int i = 0; i < 4; ++i) {
                const int ph = (sseg * 4 + i) ^ swv;
                *(bf16x8*)&Vs[half ? 0 : 1][sdv][ph * 8] = half ? vA[i] : vB[i];
            }
            const int cur = t + half;
            const bf16x8 k0f = half ? kB[0] : kA[0];
            const bf16x8 k1f = half ? kB[1] : kA[1];
            {
                const int vt  = (cur + 3 < 32) ? cur + 3 : 31;
                const int kt2 = (cur + 2 < 32) ? cur + 2 : 31;
                const bf16_t* src = Vhead + (size_t)sdv * SEQ + vt * 64 + sseg * 32;
                #pragma unroll
                for (int i = 0; i < 4; ++i) {
                    bf16x8 vv = *(const bf16x8*)(src + i * 8);
                    if (half) vA[i] = vv; else vB[i] = vv;
                }
                #pragma unroll
                for (int blk = 0; blk < 2; ++blk) {
                    bf16x8 kk = *(const bf16x8*)(
                        Kbase + (size_t)(kt2 * 64 + blk * 32 + c5) * QKD + q1 * 8);
                    if (half) kB[blk] = kk; else kA[blk] = kk;
                }
            }

            // S^T two 32x32 blocks; leaky+exp2; T12 in-register P fragments
            U8 frag[4];
            #pragma unroll
            for (int blk = 0; blk < 2; ++blk) {
                f32x16 z = {};
                f32x16 s = __builtin_amdgcn_mfma_f32_32x32x16_bf16(
                    blk ? k1f : k0f, qf, z, 0, 0, 0);
                float e[16];
                #pragma unroll
                for (int r = 0; r < 16; ++r) {
                    const float sv = s[r];
                    const float ev = __builtin_amdgcn_exp2f(fmaxf(sv, 0.2f * sv));
                    e[r] = ev;
                    li += ev;
                }
                unsigned w0 = cvtpk(e[0], e[1]),   w1 = cvtpk(e[2], e[3]);
                unsigned w2 = cvtpk(e[4], e[5]),   w3 = cvtpk(e[6], e[7]);
                unsigned w4 = cvtpk(e[8], e[9]),   w5 = cvtpk(e[10], e[11]);
                unsigned w6 = cvtpk(e[12], e[13]), w7 = cvtpk(e[14], e[15]);
                // swap vdst.hi-lanes <-> vsrc.lo-lanes: assembles contiguous kv
                plswap(w0, w2); plswap(w1, w3);    // -> frag kt = blk*2+0
                plswap(w4, w6); plswap(w5, w7);    // -> frag kt = blk*2+1
                frag[blk * 2 + 0].u[0] = w0; frag[blk * 2 + 0].u[1] = w1;
                frag[blk * 2 + 0].u[2] = w2; frag[blk * 2 + 0].u[3] = w3;
                frag[blk * 2 + 1].u[0] = w4; frag[blk * 2 + 1].u[1] = w5;
                frag[blk * 2 + 1].u[2] = w6; frag[blk * 2 + 1].u[3] = w7;
            }

            // O += P V  (pa from registers; vb from staged Vs buffer)
            __builtin_amdgcn_s_setprio(1);
            #pragma unroll
            for (int kt = 0; kt < 4; ++kt) {
                const bf16x8 pa = frag[kt].v;
                #pragma unroll
                for (int dvt = 0; dvt < 4; ++dvt) {
                    const int dv = dvt * 32 + c5;
                    const int phB = (kt * 2 + q1) ^ ((dv >> 3) & 7);
                    const bf16x8 vb = *(const bf16x8*)&Vs[half][dv][phB * 8];
                    o[dvt] = __builtin_amdgcn_mfma_f32_32x32x16_bf16(
                        pa, vb, o[dvt], 0, 0, 0);
                }
            }
            __builtin_amdgcn_s_setprio(0);
        }
    }

    li += __shfl_xor(li, 32);
    const float inv = 1.f / li;
    const float g = gptr[0];

    #pragma unroll
    for (int dvt = 0; dvt < 4; ++dvt)
        #pragma unroll
        for (int r = 0; r < 16; ++r) {
            const int row = (r & 3) + 8 * (r >> 2) + 4 * q1;
            const float linv = __shfl(inv, row);
            const size_t idx = (size_t)(b * SEQ + mbase + row) * CDIM
                             + h * DV + dvt * 32 + c5;
            out[idx] = g * (o[dvt][r] * linv) + X[idx];
        }
}

extern "C" void kernel_launch(void* const* d_in, const int* in_sizes, int n_in,
                              void* d_out, int out_size, void* d_ws, size_t ws_size,
                              hipStream_t stream) {
    const float* X  = (const float*)d_in[0];
    const float* Wq = (const float*)d_in[1];
    const float* bq = (const float*)d_in[2];
    const float* Wk = (const float*)d_in[3];
    const float* bk = (const float*)d_in[4];
    const float* Wv = (const float*)d_in[5];
    const float* bv = (const float*)d_in[6];
    const float* g  = (const float*)d_in[7];
    float* out = (float*)d_out;

    dim3 blk(256);

    // 2-launch pipeline: gemm2 (fp32 in, fused cvt) -> attn3.  21 MB ws.
    bf16_t* Qw = (bf16_t*)d_ws;                 // 8192x128
    bf16_t* Kw = Qw + (size_t)MTOT * QKD;       // 8192x128
    bf16_t* Vt = Kw + (size_t)MTOT * QKD;       // 32x128x2048

    hipLaunchKernelGGL(qkv_gemm2, dim3(10, 64), blk, 0, stream,
                       X, Wq, bq, Wk, bk, Wv, bv, Qw, Kw, Vt);
    hipLaunchKernelGGL(attn3, dim3(SEQ / 128, 32), blk, 0, stream,
                       Qw, Kw, Vt, X, g, out);
}

// Round 9
// 246.914 us; speedup vs baseline: 1.0666x; 1.0666x over previous
//
#include <hip/hip_runtime.h>
#include <hip/hip_bf16.h>

typedef __bf16 bf16_t;
typedef __bf16 bf16x8 __attribute__((ext_vector_type(8)));
typedef float f32x4 __attribute__((ext_vector_type(4)));
typedef float f32x16 __attribute__((ext_vector_type(16)));

#define MTOT 8192
#define CDIM 1024
#define HEADS 8
#define DV 128
#define QKD 128
#define SEQ 2048
#define QSCALE 0.3606737602222409f   // 0.25 * log2(e): softmax scale folded into Q

struct alignas(8) B4 { bf16_t a, b, c, d; };

__device__ inline bf16x8 cvt8(float4 a, float4 b) {
    bf16x8 v = { (bf16_t)a.x, (bf16_t)a.y, (bf16_t)a.z, (bf16_t)a.w,
                 (bf16_t)b.x, (bf16_t)b.y, (bf16_t)b.z, (bf16_t)b.w };
    return v;
}

// packed f32->bf16 pair: dst = {lo16=cvt(a), hi16=cvt(b)}  (T12; no builtin)
__device__ inline unsigned cvtpk(float a, float b) {
    unsigned r;
    asm("v_cvt_pk_bf16_f32 %0, %1, %2" : "=v"(r) : "v"(a), "v"(b));
    return r;
}

// v_permlane32_swap_b32: a.hi32lanes <-> b.lo32lanes (in place)
__device__ inline void plswap(unsigned& a, unsigned& b) {
    asm("v_permlane32_swap_b32 %0, %1" : "+v"(a), "+v"(b));
}

// ---------------------------------------------------------------------------
// QKV GEMM v4: fp32 in, in-register cvt, BM=64 x BN=128 tile, BK=64.
// grid (10, 128) = 1280 WGs (5/CU — was 640/2.5). Register prefetch of the
// next K-tile issued before the MFMA phase (latency hides under compute).
// Same proven swizzle/fragment formulas as qkv_gemm2; only wave->tile
// geometry re-parametrized (wave owns 64x32; acc[4][2]).
// bx0 -> Q (xQSCALE), bx1 -> K, bx2..9 -> V head (bx-2) transposed.
// ---------------------------------------------------------------------------
__global__ __launch_bounds__(256, 4) void qkv_gemm4(
    const float* __restrict__ X,
    const float* __restrict__ Wq, const float* __restrict__ bq,
    const float* __restrict__ Wk, const float* __restrict__ bk,
    const float* __restrict__ Wv, const float* __restrict__ bv,
    bf16_t* __restrict__ Qw, bf16_t* __restrict__ Kw, bf16_t* __restrict__ Vt)
{
    __shared__ alignas(16) bf16_t As[64][72];    // 9.2 KB
    __shared__ alignas(16) bf16_t Bs[128][72];   // 18.4 KB

    const int tid  = threadIdx.x;
    const int lane = tid & 63, wave = tid >> 6;
    const int c = lane & 15, q = lane >> 4;
    const int m0 = blockIdx.y * 64;
    const int nt_idx = blockIdx.x;

    const float* W; const float* bias;
    if (nt_idx == 0)      { W = Wq; bias = bq; }
    else if (nt_idx == 1) { W = Wk; bias = bk; }
    else { W = Wv + (size_t)(nt_idx - 2) * DV * CDIM; bias = bv + (nt_idx - 2) * DV; }

    // A staging: row = tid>>2 (0..63), seg = tid&3 (16 floats each)
    const int arow = tid >> 2, aseg = tid & 3;
    const int swa = (arow >> 3) & 3;
    const float* ax = X + (size_t)(m0 + arow) * CDIM + aseg * 16;
    // B staging: row = tid>>1 (0..127), seg = tid&1 (32 floats each)
    const int brow = tid >> 1, bseg = tid & 1;
    const int swb = (brow >> 3) & 3;
    const float* bxp = W + (size_t)brow * CDIM + bseg * 32;

    f32x4 acc[8] = {};           // [mt*2 + nt] : 64 rows x 32 cols per wave
    float4 ra[4], rb[8];         // next K-tile prefetch registers

    // prologue: load K-tile 0
    #pragma unroll
    for (int i = 0; i < 4; ++i) ra[i] = *(const float4*)(ax + i * 4);
    #pragma unroll
    for (int i = 0; i < 8; ++i) rb[i] = *(const float4*)(bxp + i * 4);

    #pragma unroll 1
    for (int k0 = 0; k0 < CDIM; k0 += 64) {
        __syncthreads();                      // MFMA readers of prev tile done
        // regs -> LDS (cvt to bf16), swizzled chunks
        *(bf16x8*)&As[arow][((aseg * 2 + 0) ^ swa) * 8] = cvt8(ra[0], ra[1]);
        *(bf16x8*)&As[arow][((aseg * 2 + 1) ^ swa) * 8] = cvt8(ra[2], ra[3]);
        #pragma unroll
        for (int i = 0; i < 4; ++i)
            *(bf16x8*)&Bs[brow][((bseg * 4 + i) ^ swb) * 8] = cvt8(rb[2 * i], rb[2 * i + 1]);

        // issue next K-tile loads (latency hidden under barrier+MFMA below)
        if (k0 + 64 < CDIM) {
            #pragma unroll
            for (int i = 0; i < 4; ++i)
                ra[i] = *(const float4*)(ax + k0 + 64 + i * 4);
            #pragma unroll
            for (int i = 0; i < 8; ++i)
                rb[i] = *(const float4*)(bxp + k0 + 64 + i * 4);
        }
        __syncthreads();                      // LDS tile ready

        #pragma unroll
        for (int kk = 0; kk < 2; ++kk) {
            bf16x8 af[4], bfr[2];
            #pragma unroll
            for (int mt = 0; mt < 4; ++mt) {
                const int row = mt * 16 + c;
                af[mt] = *(const bf16x8*)&As[row][((kk * 4 + q) ^ ((row >> 3) & 3)) * 8];
            }
            #pragma unroll
            for (int nt = 0; nt < 2; ++nt) {
                const int row = wave * 32 + nt * 16 + c;
                bfr[nt] = *(const bf16x8*)&Bs[row][((kk * 4 + q) ^ ((row >> 3) & 3)) * 8];
            }
            #pragma unroll
            for (int mt = 0; mt < 4; ++mt)
                #pragma unroll
                for (int nt = 0; nt < 2; ++nt)
                    acc[mt * 2 + nt] = __builtin_amdgcn_mfma_f32_16x16x32_bf16(
                        af[mt], bfr[nt], acc[mt * 2 + nt], 0, 0, 0);
        }
    }

    #pragma unroll
    for (int mt = 0; mt < 4; ++mt)
        #pragma unroll
        for (int nt = 0; nt < 2; ++nt) {
            const int col = wave * 32 + nt * 16 + c;   // col within this bx block
            const float bb = bias[col];
            f32x4 a = acc[mt * 2 + nt];
            const int mg = m0 + mt * 16 + q * 4;
            if (nt_idx == 0) {
                #pragma unroll
                for (int r = 0; r < 4; ++r)
                    Qw[(size_t)(mg + r) * QKD + col] = (bf16_t)((a[r] + bb) * QSCALE);
            } else if (nt_idx == 1) {
                #pragma unroll
                for (int r = 0; r < 4; ++r)
                    Kw[(size_t)(mg + r) * QKD + col] = (bf16_t)(a[r] + bb);
            } else {
                const int h = nt_idx - 2;
                const int bidx = mg >> 11, ml = mg & 2047;
                B4 v{ (bf16_t)(a[0] + bb), (bf16_t)(a[1] + bb),
                      (bf16_t)(a[2] + bb), (bf16_t)(a[3] + bb) };
                *(B4*)(Vt + ((size_t)(bidx * HEADS + h) * DV + col) * SEQ + ml) = v;
            }
        }
}

// ---------------------------------------------------------------------------
// Flash attention, 32x32x16 MFMA. One WG = one (b,h) x 128 q-rows.
// R3-exact (best measured: 64.5 us): KVBLK=64, single __syncthreads/iter,
// T12 in-register P (cvt_pk + permlane32_swap), Vs LDS double-buffer,
// 2-deep V/K register prefetch, setprio around PV, XCD-clustered mapping.
// ---------------------------------------------------------------------------
__global__ __launch_bounds__(256, 2) void attn3(
    const bf16_t* __restrict__ Q, const bf16_t* __restrict__ K,
    const bf16_t* __restrict__ Vt, const float* __restrict__ X,
    const float* __restrict__ gptr, float* __restrict__ out)
{
    __shared__ alignas(16) bf16_t Vs[2][128][72];   // 36.9 KB double buffer

    const int tid  = threadIdx.x;
    const int lane = tid & 63;
    const int c5 = lane & 31, q1 = lane >> 5;

    // XCD-cluster swizzle: each XCD gets 4 (b,h) heads x all 16 q-tiles.
    const int lin = blockIdx.x + (SEQ / 128) * blockIdx.y;  // 0..511
    const int xcd = lin & 7, jj = lin >> 3;                 // jj 0..63
    const int bh = xcd * 4 + (jj >> 4);
    const int qt = jj & 15;
    const int b = bh >> 3, h = bh & 7;
    const int wave = tid >> 6;
    const int mbase = qt * 128 + wave * 32;

    const bf16x8 qf = *(const bf16x8*)(
        Q + (size_t)(b * SEQ + mbase + c5) * QKD + h * 16 + q1 * 8);

    float li = 0.f;
    f32x16 o[4] = {};

    const bf16_t* Vhead = Vt + (size_t)(b * HEADS + h) * DV * SEQ;
    const bf16_t* Kbase = K + (size_t)(b * SEQ) * QKD + h * 16;

    const int sdv = tid >> 1, sseg = tid & 1;
    const int swv = (sdv >> 3) & 7;

    // vA: even tiles, vB: odd tiles (tile = 64 kv rows). kA even, kB odd.
    bf16x8 vA[4], vB[4], kA[2], kB[2];

    // ---- prologue: issue tiles 0 and 1 ----
    {
        const bf16_t* s0 = Vhead + (size_t)sdv * SEQ + sseg * 32;
        #pragma unroll
        for (int i = 0; i < 4; ++i) vA[i] = *(const bf16x8*)(s0 + i * 8);
        const bf16_t* s1 = s0 + 64;
        #pragma unroll
        for (int i = 0; i < 4; ++i) vB[i] = *(const bf16x8*)(s1 + i * 8);
        #pragma unroll
        for (int blk = 0; blk < 2; ++blk) {
            kA[blk] = *(const bf16x8*)(Kbase + (size_t)(blk * 32 + c5) * QKD + q1 * 8);
            kB[blk] = *(const bf16x8*)(Kbase + (size_t)(64 + blk * 32 + c5) * QKD + q1 * 8);
        }
        // write tile 0 into Vs[0]; reissue vA <- tile 2
        #pragma unroll
        for (int i = 0; i < 4; ++i) {
            const int ph = (sseg * 4 + i) ^ swv;
            *(bf16x8*)&Vs[0][sdv][ph * 8] = vA[i];
        }
        const bf16_t* s2 = s0 + 128;
        #pragma unroll
        for (int i = 0; i < 4; ++i) vA[i] = *(const bf16x8*)(s2 + i * 8);
    }

    union U8 { bf16x8 v; unsigned u[4]; };

    #pragma unroll 1
    for (int t = 0; t < 32; t += 2) {
        #pragma unroll
        for (int half = 0; half < 2; ++half) {
            // half 0: tile t   (read Vs[0], stage vB->Vs[1], reissue vB,kA)
            // half 1: tile t+1 (read Vs[1], stage vA->Vs[0], reissue vA,kB)
            __syncthreads();     // prev PV readers done; staged buffer visible
            #pragma unroll
            for (int i = 0; i < 4; ++i) {
                const int ph = (sseg * 4 + i) ^ swv;
                *(bf16x8*)&Vs[half ? 0 : 1][sdv][ph * 8] = half ? vA[i] : vB[i];
            }
            const int cur = t + half;
            const bf16x8 k0f = half ? kB[0] : kA[0];
            const bf16x8 k1f = half ? kB[1] : kA[1];
            {
                const int vt  = (cur + 3 < 32) ? cur + 3 : 31;
                const int kt2 = (cur + 2 < 32) ? cur + 2 : 31;
                const bf16_t* src = Vhead + (size_t)sdv * SEQ + vt * 64 + sseg * 32;
                #pragma unroll
                for (int i = 0; i < 4; ++i) {
                    bf16x8 vv = *(const bf16x8*)(src + i * 8);
                    if (half) vA[i] = vv; else vB[i] = vv;
                }
                #pragma unroll
                for (int blk = 0; blk < 2; ++blk) {
                    bf16x8 kk = *(const bf16x8*)(
                        Kbase + (size_t)(kt2 * 64 + blk * 32 + c5) * QKD + q1 * 8);
                    if (half) kB[blk] = kk; else kA[blk] = kk;
                }
            }

            // S^T two 32x32 blocks; leaky+exp2; T12 in-register P fragments
            U8 frag[4];
            #pragma unroll
            for (int blk = 0; blk < 2; ++blk) {
                f32x16 z = {};
                f32x16 s = __builtin_amdgcn_mfma_f32_32x32x16_bf16(
                    blk ? k1f : k0f, qf, z, 0, 0, 0);
                float e[16];
                #pragma unroll
                for (int r = 0; r < 16; ++r) {
                    const float sv = s[r];
                    const float ev = __builtin_amdgcn_exp2f(fmaxf(sv, 0.2f * sv));
                    e[r] = ev;
                    li += ev;
                }
                unsigned w0 = cvtpk(e[0], e[1]),   w1 = cvtpk(e[2], e[3]);
                unsigned w2 = cvtpk(e[4], e[5]),   w3 = cvtpk(e[6], e[7]);
                unsigned w4 = cvtpk(e[8], e[9]),   w5 = cvtpk(e[10], e[11]);
                unsigned w6 = cvtpk(e[12], e[13]), w7 = cvtpk(e[14], e[15]);
                // swap vdst.hi-lanes <-> vsrc.lo-lanes: assembles contiguous kv
                plswap(w0, w2); plswap(w1, w3);    // -> frag kt = blk*2+0
                plswap(w4, w6); plswap(w5, w7);    // -> frag kt = blk*2+1
                frag[blk * 2 + 0].u[0] = w0; frag[blk * 2 + 0].u[1] = w1;
                frag[blk * 2 + 0].u[2] = w2; frag[blk * 2 + 0].u[3] = w3;
                frag[blk * 2 + 1].u[0] = w4; frag[blk * 2 + 1].u[1] = w5;
                frag[blk * 2 + 1].u[2] = w6; frag[blk * 2 + 1].u[3] = w7;
            }

            // O += P V  (pa from registers; vb from staged Vs buffer)
            __builtin_amdgcn_s_setprio(1);
            #pragma unroll
            for (int kt = 0; kt < 4; ++kt) {
                const bf16x8 pa = frag[kt].v;
                #pragma unroll
                for (int dvt = 0; dvt < 4; ++dvt) {
                    const int dv = dvt * 32 + c5;
                    const int phB = (kt * 2 + q1) ^ ((dv >> 3) & 7);
                    const bf16x8 vb = *(const bf16x8*)&Vs[half][dv][phB * 8];
                    o[dvt] = __builtin_amdgcn_mfma_f32_32x32x16_bf16(
                        pa, vb, o[dvt], 0, 0, 0);
                }
            }
            __builtin_amdgcn_s_setprio(0);
        }
    }

    li += __shfl_xor(li, 32);
    const float inv = 1.f / li;
    const float g = gptr[0];

    #pragma unroll
    for (int dvt = 0; dvt < 4; ++dvt)
        #pragma unroll
        for (int r = 0; r < 16; ++r) {
            const int row = (r & 3) + 8 * (r >> 2) + 4 * q1;
            const float linv = __shfl(inv, row);
            const size_t idx = (size_t)(b * SEQ + mbase + row) * CDIM
                             + h * DV + dvt * 32 + c5;
            out[idx] = g * (o[dvt][r] * linv) + X[idx];
        }
}

extern "C" void kernel_launch(void* const* d_in, const int* in_sizes, int n_in,
                              void* d_out, int out_size, void* d_ws, size_t ws_size,
                              hipStream_t stream) {
    const float* X  = (const float*)d_in[0];
    const float* Wq = (const float*)d_in[1];
    const float* bq = (const float*)d_in[2];
    const float* Wk = (const float*)d_in[3];
    const float* bk = (const float*)d_in[4];
    const float* Wv = (const float*)d_in[5];
    const float* bv = (const float*)d_in[6];
    const float* g  = (const float*)d_in[7];
    float* out = (float*)d_out;

    dim3 blk(256);

    // 2-launch pipeline: gemm4 (fp32 in, fused cvt, pipelined) -> attn3. 21 MB.
    bf16_t* Qw = (bf16_t*)d_ws;                 // 8192x128
    bf16_t* Kw = Qw + (size_t)MTOT * QKD;       // 8192x128
    bf16_t* Vt = Kw + (size_t)MTOT * QKD;       // 32x128x2048

    hipLaunchKernelGGL(qkv_gemm4, dim3(10, 128), blk, 0, stream,
                       X, Wq, bq, Wk, bk, Wv, bv, Qw, Kw, Vt);
    hipLaunchKernelGGL(attn3, dim3(SEQ / 128, 32), blk, 0, stream,
                       Qw, Kw, Vt, X, g, out);
}

// Round 11
// 189.582 us; speedup vs baseline: 1.3892x; 1.3024x over previous
//
#include <hip/hip_runtime.h>
#include <hip/hip_bf16.h>

typedef __bf16 bf16_t;
typedef __bf16 bf16x8 __attribute__((ext_vector_type(8)));
typedef float f32x4 __attribute__((ext_vector_type(4)));
typedef float f32x16 __attribute__((ext_vector_type(16)));

#define MTOT 8192
#define CDIM 1024
#define HEADS 8
#define DV 128
#define QKD 128
#define SEQ 2048
#define QSCALE 0.3606737602222409f   // 0.25 * log2(e): softmax scale folded into Q

struct alignas(8) B4 { bf16_t a, b, c, d; };

__device__ inline bf16x8 cvt8(float4 a, float4 b) {
    bf16x8 v = { (bf16_t)a.x, (bf16_t)a.y, (bf16_t)a.z, (bf16_t)a.w,
                 (bf16_t)b.x, (bf16_t)b.y, (bf16_t)b.z, (bf16_t)b.w };
    return v;
}

__device__ inline void gl_lds16(const bf16_t* g, bf16_t* l) {
    __builtin_amdgcn_global_load_lds(
        (const __attribute__((address_space(1))) void*)g,
        (__attribute__((address_space(3))) void*)l, 16, 0, 0);
}

// packed f32->bf16 pair: dst = {lo16=cvt(a), hi16=cvt(b)}  (T12; no builtin)
__device__ inline unsigned cvtpk(float a, float b) {
    unsigned r;
    asm("v_cvt_pk_bf16_f32 %0, %1, %2" : "=v"(r) : "v"(a), "v"(b));
    return r;
}

// v_permlane32_swap_b32: a.hi32lanes <-> b.lo32lanes (in place)
__device__ inline void plswap(unsigned& a, unsigned& b) {
    asm("v_permlane32_swap_b32 %0, %1" : "+v"(a), "+v"(b));
}

// ---------------------------------------------------------------------------
// Fused fp32 -> bf16 conversion: X (1M items) + Wq|Wk|Wv (160K items).
// ---------------------------------------------------------------------------
#define XITEMS (MTOT * CDIM / 8)          // 1048576
#define WITEMS (1280 * CDIM / 8)          // 163840

__global__ __launch_bounds__(256) void cvt_all(
    const float* __restrict__ X,
    const float* __restrict__ Wq, const float* __restrict__ Wk,
    const float* __restrict__ Wv,
    bf16_t* __restrict__ Xb, bf16_t* __restrict__ Wb)
{
    int i = blockIdx.x * blockDim.x + threadIdx.x;
    if (i < XITEMS) {
        const float4* s = reinterpret_cast<const float4*>(X) + (size_t)i * 2;
        reinterpret_cast<bf16x8*>(Xb)[i] = cvt8(s[0], s[1]);
    } else {
        int j = i - XITEMS;
        const float* src;
        if (j < 16384)       src = Wq + (size_t)j * 8;
        else if (j < 32768)  src = Wk + (size_t)(j - 16384) * 8;
        else                 src = Wv + (size_t)(j - 32768) * 8;
        const float4* s = reinterpret_cast<const float4*>(src);
        reinterpret_cast<bf16x8*>(Wb)[j] = cvt8(s[0], s[1]);
    }
}

// ---------------------------------------------------------------------------
// QKV GEMM v5: gemm3 (m97-structure, bf16 in, global_load_lds 16B) with
// BM 128->64 for occupancy: grid (10,128) = 1280 WGs (~5/CU vs 2.5),
// LDS 24KB, acc 32 VGPR. Staging/fragment/epilogue formulas verbatim
// from gemm3. Cross-block overlap hides the per-step barrier drain.
// bx0 -> Q (xQSCALE), bx1 -> K, bx2..9 -> V head (bx-2) transposed.
// ---------------------------------------------------------------------------
__global__ __launch_bounds__(256, 4) void qkv_gemm5(
    const bf16_t* __restrict__ Xb, const bf16_t* __restrict__ Wb,
    const float* __restrict__ bq, const float* __restrict__ bk,
    const float* __restrict__ bv,
    bf16_t* __restrict__ Qw, bf16_t* __restrict__ Kw, bf16_t* __restrict__ Vt)
{
    __shared__ bf16_t As[64][64];    // 8 KB
    __shared__ bf16_t Bs[128][64];   // 16 KB

    const int tid = threadIdx.x;
    const int w = tid >> 6, l = tid & 63;
    const int c = l & 15, q = l >> 4;
    const int bx = blockIdx.x;
    const int m0 = blockIdx.y * 64;

    const bf16_t* Arow = Xb + (size_t)(m0 + w * 8 + (l >> 3)) * CDIM + (l & 7) * 8;
    const bf16_t* Brow = Wb + (size_t)(bx * 128 + w * 8 + (l >> 3)) * CDIM + (l & 7) * 8;

    f32x4 acc[8] = {};   // [mt*2 + nt]: 64 rows x (wave's 32 cols)

    for (int k0 = 0; k0 < CDIM; k0 += 64) {
        __syncthreads();
        #pragma unroll
        for (int i = 0; i < 2; ++i)
            gl_lds16(Arow + k0 + (size_t)i * 32 * CDIM, &As[i * 32 + w * 8][0]);
        #pragma unroll
        for (int i = 0; i < 4; ++i)
            gl_lds16(Brow + k0 + (size_t)i * 32 * CDIM, &Bs[i * 32 + w * 8][0]);
        __syncthreads();
        #pragma unroll
        for (int kk = 0; kk < 2; ++kk) {
            bf16x8 af[4], bfr[2];
            #pragma unroll
            for (int mt = 0; mt < 4; ++mt)
                af[mt] = *(const bf16x8*)&As[mt * 16 + c][kk * 32 + q * 8];
            #pragma unroll
            for (int nt = 0; nt < 2; ++nt)
                bfr[nt] = *(const bf16x8*)&Bs[w * 32 + nt * 16 + c][kk * 32 + q * 8];
            #pragma unroll
            for (int mt = 0; mt < 4; ++mt)
                #pragma unroll
                for (int nt = 0; nt < 2; ++nt)
                    acc[mt * 2 + nt] = __builtin_amdgcn_mfma_f32_16x16x32_bf16(
                        af[mt], bfr[nt], acc[mt * 2 + nt], 0, 0, 0);
        }
    }

    #pragma unroll
    for (int mt = 0; mt < 4; ++mt)
        #pragma unroll
        for (int nt = 0; nt < 2; ++nt) {
            const int cl = w * 32 + nt * 16 + c;       // col within this bx block
            f32x4 a = acc[mt * 2 + nt];
            const int mg = m0 + mt * 16 + q * 4;
            if (bx == 0) {
                const float bb = bq[cl];
                #pragma unroll
                for (int r = 0; r < 4; ++r)
                    Qw[(size_t)(mg + r) * QKD + cl] = (bf16_t)((a[r] + bb) * QSCALE);
            } else if (bx == 1) {
                const float bb = bk[cl];
                #pragma unroll
                for (int r = 0; r < 4; ++r)
                    Kw[(size_t)(mg + r) * QKD + cl] = (bf16_t)(a[r] + bb);
            } else {
                const int h = bx - 2;
                const float bb = bv[h * DV + cl];
                const int bidx = mg >> 11, ml = mg & 2047;
                B4 v{ (bf16_t)(a[0] + bb), (bf16_t)(a[1] + bb),
                      (bf16_t)(a[2] + bb), (bf16_t)(a[3] + bb) };
                *(B4*)(Vt + ((size_t)(bidx * HEADS + h) * DV + cl) * SEQ + ml) = v;
            }
        }
}

// ---------------------------------------------------------------------------
// Fallback fp32-input GEMM (R7-proven): LDS-staged 128x128, in-register cvt.
// ---------------------------------------------------------------------------
__global__ __launch_bounds__(256, 2) void qkv_gemm2(
    const float* __restrict__ X,
    const float* __restrict__ Wq, const float* __restrict__ bq,
    const float* __restrict__ Wk, const float* __restrict__ bk,
    const float* __restrict__ Wv, const float* __restrict__ bv,
    bf16_t* __restrict__ Qw, bf16_t* __restrict__ Kw, bf16_t* __restrict__ Vt)
{
    __shared__ alignas(16) bf16_t As[128][72];
    __shared__ alignas(16) bf16_t Bs[128][72];

    const int tid  = threadIdx.x;
    const int lane = tid & 63, wave = tid >> 6;
    const int c = lane & 15, q = lane >> 4;
    const int rw = wave & 1, cw = wave >> 1;
    const int m0 = blockIdx.y * 128;
    const int nt_idx = blockIdx.x;

    const float* W; const float* bias;
    if (nt_idx == 0)      { W = Wq; bias = bq; }
    else if (nt_idx == 1) { W = Wk; bias = bk; }
    else { W = Wv + (size_t)(nt_idx - 2) * DV * CDIM; bias = bv + (nt_idx - 2) * DV; }

    const int srow = tid >> 1, sseg = tid & 1;
    const int swr = (srow >> 3) & 3;
    const float* ax = X + (size_t)(m0 + srow) * CDIM + sseg * 32;
    const float* bxp = W + (size_t)srow * CDIM + sseg * 32;

    f32x4 acc[16] = {};

    for (int k0 = 0; k0 < CDIM; k0 += 64) {
        __syncthreads();
        #pragma unroll
        for (int i = 0; i < 4; ++i) {
            const int ph = (sseg * 4 + i) ^ swr;
            *(bf16x8*)&As[srow][ph * 8] = cvt8(*(const float4*)(ax + k0 + i * 8),
                                               *(const float4*)(ax + k0 + i * 8 + 4));
            *(bf16x8*)&Bs[srow][ph * 8] = cvt8(*(const float4*)(bxp + k0 + i * 8),
                                               *(const float4*)(bxp + k0 + i * 8 + 4));
        }
        __syncthreads();
        #pragma unroll
        for (int kk = 0; kk < 2; ++kk) {
            bf16x8 af[4], bfr[4];
            #pragma unroll
            for (int mt = 0; mt < 4; ++mt) {
                const int row = rw * 64 + mt * 16 + c;
                af[mt] = *(const bf16x8*)&As[row][((kk * 4 + q) ^ ((row >> 3) & 3)) * 8];
            }
            #pragma unroll
            for (int nt = 0; nt < 4; ++nt) {
                const int row = cw * 64 + nt * 16 + c;
                bfr[nt] = *(const bf16x8*)&Bs[row][((kk * 4 + q) ^ ((row >> 3) & 3)) * 8];
            }
            #pragma unroll
            for (int mt = 0; mt < 4; ++mt)
                #pragma unroll
                for (int nt = 0; nt < 4; ++nt)
                    acc[mt * 4 + nt] = __builtin_amdgcn_mfma_f32_16x16x32_bf16(
                        af[mt], bfr[nt], acc[mt * 4 + nt], 0, 0, 0);
        }
    }

    #pragma unroll
    for (int mt = 0; mt < 4; ++mt)
        #pragma unroll
        for (int nt = 0; nt < 4; ++nt) {
            const int col = cw * 64 + nt * 16 + c;
            const float bb = bias[col];
            f32x4 a = acc[mt * 4 + nt];
            const int mg = m0 + rw * 64 + mt * 16 + q * 4;
            if (nt_idx == 0) {
                #pragma unroll
                for (int r = 0; r < 4; ++r)
                    Qw[(size_t)(mg + r) * QKD + col] = (bf16_t)((a[r] + bb) * QSCALE);
            } else if (nt_idx == 1) {
                #pragma unroll
                for (int r = 0; r < 4; ++r)
                    Kw[(size_t)(mg + r) * QKD + col] = (bf16_t)(a[r] + bb);
            } else {
                const int h = nt_idx - 2;
                const int bidx = mg >> 11, ml = mg & 2047;
                B4 v{ (bf16_t)(a[0] + bb), (bf16_t)(a[1] + bb),
                      (bf16_t)(a[2] + bb), (bf16_t)(a[3] + bb) };
                *(B4*)(Vt + ((size_t)(bidx * HEADS + h) * DV + col) * SEQ + ml) = v;
            }
        }
}

// ---------------------------------------------------------------------------
// Flash attention, 32x32x16 MFMA. One WG = one (b,h) x 128 q-rows.
// R3-exact (best measured: 64.5 us): KVBLK=64, single __syncthreads/iter,
// T12 in-register P (cvt_pk + permlane32_swap), Vs LDS double-buffer,
// 2-deep V/K register prefetch, setprio around PV, XCD-clustered mapping.
// ---------------------------------------------------------------------------
__global__ __launch_bounds__(256, 2) void attn3(
    const bf16_t* __restrict__ Q, const bf16_t* __restrict__ K,
    const bf16_t* __restrict__ Vt, const float* __restrict__ X,
    const float* __restrict__ gptr, float* __restrict__ out)
{
    __shared__ alignas(16) bf16_t Vs[2][128][72];   // 36.9 KB double buffer

    const int tid  = threadIdx.x;
    const int lane = tid & 63;
    const int c5 = lane & 31, q1 = lane >> 5;

    // XCD-cluster swizzle: each XCD gets 4 (b,h) heads x all 16 q-tiles.
    const int lin = blockIdx.x + (SEQ / 128) * blockIdx.y;  // 0..511
    const int xcd = lin & 7, jj = lin >> 3;                 // jj 0..63
    const int bh = xcd * 4 + (jj >> 4);
    const int qt = jj & 15;
    const int b = bh >> 3, h = bh & 7;
    const int wave = tid >> 6;
    const int mbase = qt * 128 + wave * 32;

    const bf16x8 qf = *(const bf16x8*)(
        Q + (size_t)(b * SEQ + mbase + c5) * QKD + h * 16 + q1 * 8);

    float li = 0.f;
    f32x16 o[4] = {};

    const bf16_t* Vhead = Vt + (size_t)(b * HEADS + h) * DV * SEQ;
    const bf16_t* Kbase = K + (size_t)(b * SEQ) * QKD + h * 16;

    const int sdv = tid >> 1, sseg = tid & 1;
    const int swv = (sdv >> 3) & 7;

    // vA: even tiles, vB: odd tiles (tile = 64 kv rows). kA even, kB odd.
    bf16x8 vA[4], vB[4], kA[2], kB[2];

    // ---- prologue: issue tiles 0 and 1 ----
    {
        const bf16_t* s0 = Vhead + (size_t)sdv * SEQ + sseg * 32;
        #pragma unroll
        for (int i = 0; i < 4; ++i) vA[i] = *(const bf16x8*)(s0 + i * 8);
        const bf16_t* s1 = s0 + 64;
        #pragma unroll
        for (int i = 0; i < 4; ++i) vB[i] = *(const bf16x8*)(s1 + i * 8);
        #pragma unroll
        for (int blk = 0; blk < 2; ++blk) {
            kA[blk] = *(const bf16x8*)(Kbase + (size_t)(blk * 32 + c5) * QKD + q1 * 8);
            kB[blk] = *(const bf16x8*)(Kbase + (size_t)(64 + blk * 32 + c5) * QKD + q1 * 8);
        }
        // write tile 0 into Vs[0]; reissue vA <- tile 2
        #pragma unroll
        for (int i = 0; i < 4; ++i) {
            const int ph = (sseg * 4 + i) ^ swv;
            *(bf16x8*)&Vs[0][sdv][ph * 8] = vA[i];
        }
        const bf16_t* s2 = s0 + 128;
        #pragma unroll
        for (int i = 0; i < 4; ++i) vA[i] = *(const bf16x8*)(s2 + i * 8);
    }

    union U8 { bf16x8 v; unsigned u[4]; };

    #pragma unroll 1
    for (int t = 0; t < 32; t += 2) {
        #pragma unroll
        for (int half = 0; half < 2; ++half) {
            // half 0: tile t   (read Vs[0], stage vB->Vs[1], reissue vB,kA)
            // half 1: tile t+1 (read Vs[1], stage vA->Vs[0], reissue vA,kB)
            __syncthreads();     // prev PV readers done; staged buffer visible
            #pragma unroll
            for (int i = 0; i < 4; ++i) {
                const int ph = (sseg * 4 + i) ^ swv;
                *(bf16x8*)&Vs[half ? 0 : 1][sdv][ph * 8] = half ? vA[i] : vB[i];
            }
            const int cur = t + half;
            const bf16x8 k0f = half ? kB[0] : kA[0];
            const bf16x8 k1f = half ? kB[1] : kA[1];
            {
                const int vt  = (cur + 3 < 32) ? cur + 3 : 31;
                const int kt2 = (cur + 2 < 32) ? cur + 2 : 31;
                const bf16_t* src = Vhead + (size_t)sdv * SEQ + vt * 64 + sseg * 32;
                #pragma unroll
                for (int i = 0; i < 4; ++i) {
                    bf16x8 vv = *(const bf16x8*)(src + i * 8);
                    if (half) vA[i] = vv; else vB[i] = vv;
                }
                #pragma unroll
                for (int blk = 0; blk < 2; ++blk) {
                    bf16x8 kk = *(const bf16x8*)(
                        Kbase + (size_t)(kt2 * 64 + blk * 32 + c5) * QKD + q1 * 8);
                    if (half) kB[blk] = kk; else kA[blk] = kk;
                }
            }

            // S^T two 32x32 blocks; leaky+exp2; T12 in-register P fragments
            U8 frag[4];
            #pragma unroll
            for (int blk = 0; blk < 2; ++blk) {
                f32x16 z = {};
                f32x16 s = __builtin_amdgcn_mfma_f32_32x32x16_bf16(
                    blk ? k1f : k0f, qf, z, 0, 0, 0);
                float e[16];
                #pragma unroll
                for (int r = 0; r < 16; ++r) {
                    const float sv = s[r];
                    const float ev = __builtin_amdgcn_exp2f(fmaxf(sv, 0.2f * sv));
                    e[r] = ev;
                    li += ev;
                }
                unsigned w0 = cvtpk(e[0], e[1]),   w1 = cvtpk(e[2], e[3]);
                unsigned w2 = cvtpk(e[4], e[5]),   w3 = cvtpk(e[6], e[7]);
                unsigned w4 = cvtpk(e[8], e[9]),   w5 = cvtpk(e[10], e[11]);
                unsigned w6 = cvtpk(e[12], e[13]), w7 = cvtpk(e[14], e[15]);
                // swap vdst.hi-lanes <-> vsrc.lo-lanes: assembles contiguous kv
                plswap(w0, w2); plswap(w1, w3);    // -> frag kt = blk*2+0
                plswap(w4, w6); plswap(w5, w7);    // -> frag kt = blk*2+1
                frag[blk * 2 + 0].u[0] = w0; frag[blk * 2 + 0].u[1] = w1;
                frag[blk * 2 + 0].u[2] = w2; frag[blk * 2 + 0].u[3] = w3;
                frag[blk * 2 + 1].u[0] = w4; frag[blk * 2 + 1].u[1] = w5;
                frag[blk * 2 + 1].u[2] = w6; frag[blk * 2 + 1].u[3] = w7;
            }

            // O += P V  (pa from registers; vb from staged Vs buffer)
            __builtin_amdgcn_s_setprio(1);
            #pragma unroll
            for (int kt = 0; kt < 4; ++kt) {
                const bf16x8 pa = frag[kt].v;
                #pragma unroll
                for (int dvt = 0; dvt < 4; ++dvt) {
                    const int dv = dvt * 32 + c5;
                    const int phB = (kt * 2 + q1) ^ ((dv >> 3) & 7);
                    const bf16x8 vb = *(const bf16x8*)&Vs[half][dv][phB * 8];
                    o[dvt] = __builtin_amdgcn_mfma_f32_32x32x16_bf16(
                        pa, vb, o[dvt], 0, 0, 0);
                }
            }
            __builtin_amdgcn_s_setprio(0);
        }
    }

    li += __shfl_xor(li, 32);
    const float inv = 1.f / li;
    const float g = gptr[0];

    #pragma unroll
    for (int dvt = 0; dvt < 4; ++dvt)
        #pragma unroll
        for (int r = 0; r < 16; ++r) {
            const int row = (r & 3) + 8 * (r >> 2) + 4 * q1;
            const float linv = __shfl(inv, row);
            const size_t idx = (size_t)(b * SEQ + mbase + row) * CDIM
                             + h * DV + dvt * 32 + c5;
            out[idx] = g * (o[dvt][r] * linv) + X[idx];
        }
}

extern "C" void kernel_launch(void* const* d_in, const int* in_sizes, int n_in,
                              void* d_out, int out_size, void* d_ws, size_t ws_size,
                              hipStream_t stream) {
    const float* X  = (const float*)d_in[0];
    const float* Wq = (const float*)d_in[1];
    const float* bq = (const float*)d_in[2];
    const float* Wk = (const float*)d_in[3];
    const float* bk = (const float*)d_in[4];
    const float* Wv = (const float*)d_in[5];
    const float* bv = (const float*)d_in[6];
    const float* g  = (const float*)d_in[7];
    float* out = (float*)d_out;

    dim3 blk(256);
    const size_t big_elems = (size_t)MTOT * CDIM + 1280 * CDIM
                           + (size_t)MTOT * QKD * 2 + (size_t)MTOT * CDIM;
    const size_t big_ws = big_elems * sizeof(bf16_t);   // 40.4 MB

    if (ws_size >= big_ws) {
        bf16_t* Xb = (bf16_t*)d_ws;                        // 8192x1024
        bf16_t* Wb = Xb + (size_t)MTOT * CDIM;             // 1280x1024
        bf16_t* Qw = Wb + (size_t)1280 * CDIM;             // 8192x128
        bf16_t* Kw = Qw + (size_t)MTOT * QKD;
        bf16_t* Vt = Kw + (size_t)MTOT * QKD;              // 32x128x2048

        hipLaunchKernelGGL(cvt_all, dim3((XITEMS + WITEMS) / 256), blk, 0, stream,
                           X, Wq, Wk, Wv, Xb, Wb);
        hipLaunchKernelGGL(qkv_gemm5, dim3(10, 128), blk, 0, stream,
                           Xb, Wb, bq, bk, bv, Qw, Kw, Vt);
        hipLaunchKernelGGL(attn3, dim3(SEQ / 128, 32), blk, 0, stream,
                           Qw, Kw, Vt, X, g, out);
    } else {
        // 21 MB fallback (R7-proven)
        bf16_t* Qw = (bf16_t*)d_ws;
        bf16_t* Kw = Qw + (size_t)MTOT * QKD;
        bf16_t* Vt = Kw + (size_t)MTOT * QKD;
        hipLaunchKernelGGL(qkv_gemm2, dim3(10, 64), blk, 0, stream,
                           X, Wq, bq, Wk, bk, Wv, bv, Qw, Kw, Vt);
        hipLaunchKernelGGL(attn3, dim3(SEQ / 128, 32), blk, 0, stream,
                           Qw, Kw, Vt, X, g, out);
    }
}